// Round 7
// baseline (86.690 us; speedup 1.0000x reference)
//
#include <hip/hip_runtime.h>

#define Hh 512
#define Ww 512
#define NPIX (Hh*Ww)
#define BATCH 4

// ws layout (no initialization required anywhere):
//   bmin: float[4][256]        @ 0      (4 KB)  per-block S min (plain stores)
//   bmax: float[4][256]        @ 4096   (4 KB)  per-block S max
//   hp:   uint [4][64bin][64s] @ 8192   (64 KB) per-block partial histograms (transposed)

__global__ __launch_bounds__(256) void k_hist(const float* __restrict__ in,
                                              unsigned* __restrict__ hp) {
    __shared__ unsigned lh[64];
    const int tid = threadIdx.x;
    if (tid < 64) lh[tid] = 0u;
    __syncthreads();
    const int img = blockIdx.x >> 6, sub = blockIdx.x & 63;
    const float4* Lp = (const float4*)(in + (size_t)img * 3 * NPIX) + sub * 1024;
    #pragma unroll
    for (int t = 0; t < 4; ++t) {
        float4 v = Lp[t*256 + tid];
        float f[4] = {v.x, v.y, v.z, v.w};
        #pragma unroll
        for (int j = 0; j < 4; ++j) {
            float ln = fminf(fmaxf(f[j] / 100.0f, 0.0f), 1.0f);
            int idx = min((int)(ln * 64.0f), 63);
            atomicAdd(&lh[idx], 1u);
        }
    }
    __syncthreads();
    if (tid < 64) hp[((size_t)img*64 + tid)*64 + sub] = lh[tid];   // [img][bin][sub]
}

// Tile 16 wide x 64 tall; block 16x16; 4 vertical outputs/thread (streaming).
// Staged: 78 rows x 32 cols at (by-7, bx-8). Packed-bin row stride 9 dwords
// (dword 8 dead; reads of it are fully masked by wm).
__global__ __launch_bounds__(256, 4) void k_main(const float* __restrict__ in,
        const unsigned* __restrict__ hp, float* __restrict__ bmin,
        float* __restrict__ bmax, float* __restrict__ out)
{
    __shared__ unsigned s_pk[78*9];
    __shared__ float s_c[78*36];
    __shared__ float s_cc[64*33];
    __shared__ float s_lnc[64*16];
    __shared__ float lhf[64];
    __shared__ float red[8];

    const int tx = threadIdx.x, ty = threadIdx.y;
    const int tid = ty*16 + tx;
    const int bx = blockIdx.x * 16, by = blockIdx.y * 64;
    const int img = blockIdx.z;
    const float* Lp = in + (size_t)img * 3 * NPIX;

    // ---- phase 0: coalesced hist reduce (all 256 threads, 4 uint4 each) ----
    {
        const int bin = tid >> 2, grp = tid & 3;
        const uint4* p = (const uint4*)(hp + ((size_t)img*64 + bin)*64 + grp*16);
        uint4 x0 = p[0], x1 = p[1], x2 = p[2], x3 = p[3];
        unsigned sum = x0.x+x0.y+x0.z+x0.w + x1.x+x1.y+x1.z+x1.w
                     + x2.x+x2.y+x2.z+x2.w + x3.x+x3.y+x3.z+x3.w;
        sum += __shfl_xor(sum, 1);
        sum += __shfl_xor(sum, 2);
        if (grp == 0) lhf[bin] = (float)sum * (1.0f/262144.0f);
    }

    // ---- per-thread window byte masks (5 dwords, high bit per window byte) ----
    const int s = tx + 1;
    const int j0 = s >> 2;
    const unsigned m20 = 0x7FFFu << (s & 3);
    unsigned wm[5];
    #pragma unroll
    for (int i = 0; i < 5; ++i) {
        unsigned n = (m20 >> (4*i)) & 0xFu;
        wm[i] = (n&1u)*0x80u | (n&2u)*0x4000u | (n&4u)*0x200000u | (n&8u)*0x10000000u;
    }

    // ---- stage 78x32 (624 quads): prefetch all global loads first ----
    float4 Lv[3], Av[3], Bv[3];
    bool vld[3];
    #pragma unroll
    for (int it = 0; it < 3; ++it) {
        const int l = tid + it*256;
        const int r = l >> 3, c4 = l & 7;
        const int gy = by - 7 + r, gx0 = bx - 8 + c4*4;
        vld[it] = (l < 624) && gy >= 0 && gy < Hh && gx0 >= 0 && gx0 < Ww;
        if (vld[it]) {
            const int g = gy*Ww + gx0;
            Lv[it] = *(const float4*)(Lp + g);
            Av[it] = *(const float4*)(Lp + NPIX + g);
            Bv[it] = *(const float4*)(Lp + 2*NPIX + g);
        }
    }
    #pragma unroll
    for (int it = 0; it < 3; ++it) {
        const int l = tid + it*256;
        if (l < 624) {
            const int r = l >> 3, c4 = l & 7;
            unsigned pk = 0x7F7F7F7Fu;
            float4 cv = {0.f, 0.f, 0.f, 0.f};
            if (vld[it]) {
                const float l0 = fminf(fmaxf(Lv[it].x / 100.0f, 0.0f), 1.0f);
                const float l1 = fminf(fmaxf(Lv[it].y / 100.0f, 0.0f), 1.0f);
                const float l2 = fminf(fmaxf(Lv[it].z / 100.0f, 0.0f), 1.0f);
                const float l3 = fminf(fmaxf(Lv[it].w / 100.0f, 0.0f), 1.0f);
                const int b0 = min((int)(l0*64.0f), 63), b1 = min((int)(l1*64.0f), 63);
                const int b2 = min((int)(l2*64.0f), 63), b3 = min((int)(l3*64.0f), 63);
                pk = (unsigned)b0 | ((unsigned)b1<<8) | ((unsigned)b2<<16) | ((unsigned)b3<<24);
                const float k255 = 1.0f/255.0f;
                cv.x = (Av[it].x+128.0f)*k255 + (Bv[it].x+128.0f)*k255;
                cv.y = (Av[it].y+128.0f)*k255 + (Bv[it].y+128.0f)*k255;
                cv.z = (Av[it].z+128.0f)*k255 + (Bv[it].z+128.0f)*k255;
                cv.w = (Av[it].w+128.0f)*k255 + (Bv[it].w+128.0f)*k255;
                if (r >= 7 && r < 71 && c4 >= 2 && c4 <= 5) {
                    float4 lv4 = {l0, l1, l2, l3};
                    *(float4*)&s_lnc[(r-7)*16 + 4*(c4-2)] = lv4;
                }
            }
            s_pk[r*9 + c4] = pk;
            *(float4*)&s_c[r*36 + c4*4] = cv;
        }
    }
    __syncthreads();

    // ---- vertical chroma 15-sums via sliding window: 31 cols x 8 row-groups ----
    if (tid < 248) {
        const int grp = tid / 31;         // 0..7 -> output rows grp*8 .. grp*8+7
        const int col = tid - grp*31;     // 0..30
        const int r0v = grp*8;
        float sum = 0.f;
        #pragma unroll
        for (int k = 0; k < 15; ++k) sum += s_c[(r0v+k)*36 + col];
        s_cc[r0v*33 + col] = sum;
        #pragma unroll
        for (int jj = 1; jj < 8; ++jj) {
            sum += s_c[(r0v+14+jj)*36 + col] - s_c[(r0v+jj-1)*36 + col];
            s_cc[(r0v+jj)*33 + col] = sum;
        }
    }
    __syncthreads();

    // ---- own-bin match: stream 18 rows, 4 outputs/thread, 4 indep chains ----
    const int r0 = 4*ty;                  // output-row base within tile
    const int cb_dw = (tx+8) >> 2, cb_sh = 8*((tx+8)&3);
    unsigned cbb[4], cb4[4];
    #pragma unroll
    for (int j = 0; j < 4; ++j) {
        cbb[j] = (s_pk[(r0+7+j)*9 + cb_dw] >> cb_sh) & 0xFFu;
        cb4[j] = cbb[j] * 0x01010101u;
    }
    const unsigned K = 0x7F7F7F7Fu;
    int acc[4] = {0,0,0,0};
    const unsigned* rp = s_pk + r0*9 + j0;

    #pragma unroll
    for (int k = 0; k < 18; ++k) {
        const unsigned d0 = rp[k*9+0], d1 = rp[k*9+1], d2 = rp[k*9+2],
                       d3 = rp[k*9+3], d4 = rp[k*9+4];
        #pragma unroll
        for (int j = 0; j < 4; ++j) {
            if (j <= k && k <= j + 14) {
                acc[j] += __popc(~((d0^cb4[j])+K) & wm[0]);
                acc[j] += __popc(~((d1^cb4[j])+K) & wm[1]);
                acc[j] += __popc(~((d2^cb4[j])+K) & wm[2]);
                acc[j] += __popc(~((d3^cb4[j])+K) & wm[3]);
                acc[j] += __popc(~((d4^cb4[j])+K) & wm[4]);
            }
        }
    }

    // ---- horizontal chroma sums (15 cols per output row) ----
    float sc[4] = {0.f, 0.f, 0.f, 0.f};
    #pragma unroll
    for (int j = 0; j < 4; ++j) {
        const float* ccp = s_cc + (r0+j)*33 + s;
        #pragma unroll
        for (int dx = 0; dx < 15; ++dx) sc[j] += ccp[dx];
    }

    // ---- epilogue: S (to out second half), L_perp, per-thread min/max ----
    const int gx = bx + tx;
    const int cols = min(gx+7, Ww-1) - max(gx-7, 0) + 1;
    float* outN = out + (size_t)BATCH*NPIX;
    float smin = __builtin_inff(), smax = -__builtin_inff();
    #pragma unroll
    for (int j = 0; j < 4; ++j) {
        const int gy = by + r0 + j;
        const int rows = min(gy+7, Hh-1) - max(gy-7, 0) + 1;
        const float invn = __builtin_amdgcn_rcpf((float)(rows*cols));
        const float S = -__logf(0.9f*((float)acc[j]*invn) + 0.1f*lhf[cbb[j]] + 1e-6f);
        const int gbase = img*NPIX + gy*Ww + gx;
        outN[gbase] = S;
        const float lp = s_lnc[(r0+j)*16 + tx]
                       - 0.5f*(s_c[(r0+7+j)*36 + tx+8] - sc[j]*invn);
        out[gbase] = fminf(fmaxf(lp, 0.f), 1.f);
        smin = fminf(smin, S); smax = fmaxf(smax, S);
    }

    // ---- block min/max of S -> plain per-block stores (no atomics/init) ----
    #pragma unroll
    for (int off = 32; off >= 1; off >>= 1) {
        smin = fminf(smin, __shfl_xor(smin, off));
        smax = fmaxf(smax, __shfl_xor(smax, off));
    }
    const int wid = tid >> 6;
    if ((tid & 63) == 0) { red[wid] = smin; red[4+wid] = smax; }
    __syncthreads();
    if (tid == 0) {
        const int bid = blockIdx.y*32 + blockIdx.x;   // 256 blocks/image
        bmin[img*256 + bid] = fminf(fminf(red[0],red[1]), fminf(red[2],red[3]));
        bmax[img*256 + bid] = fmaxf(fmaxf(red[4],red[5]), fmaxf(red[6],red[7]));
    }
}

// In-place normalize of outN. 1024 blocks x 256 threads; 1 float4/thread.
__global__ __launch_bounds__(256) void k_norm(float* __restrict__ outN,
        const float* __restrict__ bmin, const float* __restrict__ bmax) {
    __shared__ float red[2];
    const int tid = threadIdx.x;
    const int img = blockIdx.x >> 8;

    if (tid < 64) {   // exactly wave 0: 64 float4 = 256 partials per image
        float4 a = ((const float4*)(bmin + img*256))[tid];
        float4 b = ((const float4*)(bmax + img*256))[tid];
        float mn = fminf(fminf(a.x, a.y), fminf(a.z, a.w));
        float mx = fmaxf(fmaxf(b.x, b.y), fmaxf(b.z, b.w));
        #pragma unroll
        for (int off = 32; off >= 1; off >>= 1) {
            mn = fminf(mn, __shfl_xor(mn, off));
            mx = fmaxf(mx, __shfl_xor(mx, off));
        }
        if (tid == 0) { red[0] = mn; red[1] = mx; }
    }
    __syncthreads();
    const float vmin = red[0];
    const float inv = 1.0f / (red[1] - vmin + 1e-6f);

    float4* p = (float4*)outN + (size_t)blockIdx.x*256;
    float4 v = p[tid];
    v.x = (v.x - vmin) * inv; v.y = (v.y - vmin) * inv;
    v.z = (v.z - vmin) * inv; v.w = (v.w - vmin) * inv;
    p[tid] = v;
}

extern "C" void kernel_launch(void* const* d_in, const int* in_sizes, int n_in,
                              void* d_out, int out_size, void* d_ws, size_t ws_size,
                              hipStream_t stream) {
    const float* in = (const float*)d_in[0];
    float* out = (float*)d_out;
    float* bmin = (float*)d_ws;                          // 4 KB
    float* bmax = bmin + BATCH*256;                      // 4 KB
    unsigned* hp = (unsigned*)(bmax + BATCH*256);        // 64 KB

    k_hist<<<BATCH*64, 256, 0, stream>>>(in, hp);
    dim3 grid(Ww/16, Hh/64, BATCH), blk(16, 16);
    k_main<<<grid, blk, 0, stream>>>(in, hp, bmin, bmax, out);
    k_norm<<<BATCH*256, 256, 0, stream>>>(out + (size_t)BATCH*NPIX, bmin, bmax);
}